// Round 4
// baseline (81.470 us; speedup 1.0000x reference)
//
#include <hip/hip_runtime.h>
#include <stdint.h>

// Bit-serial conv2d closed form: term = sign(w) * ((x * |w|) >> 4)
//                                     = (x * w + A) >> 4   [arith shift]
// where A = (w<0) ? 15 : 0.  x in [0,15], w in [-8,7].
// out = relu(bias + sum_{3x3,c} term).  B=4 H=32 W=32 C=64 F=128.
// Exact in i16 (per-thread |acc| <= 7*144 = 1008).

typedef short s16x2 __attribute__((ext_vector_type(2)));

#define NWPK 36864            // 9*2*512*4 packed weight dwords (2 i16 each)
#define XOFF 36864            // dword offset of padded x in ws
#define NXPK 147968           // 4*34*34*32 padded input dwords (2 i16 each)

// blocks [0,144): weight pack (VGPR-slice layout); [144,723): pad+pack x.
// Weight dword index: ((ki*2+g)*512 + cq*128 + f)*4 + u
//   holds channels c = cq*16 + g*8 + u*2 and c+1 for filter f, position ki.
// -> consumer thread tid=cq*128+f loads int4 at [ (ki*2+g)*512 + tid ], coalesced.
__global__ __launch_bounds__(256) void prep_all(const float* __restrict__ kern,
                                                const float* __restrict__ input,
                                                uint32_t* __restrict__ ws) {
    int bid = blockIdx.x, tid = threadIdx.x;
    if (bid < 144) {
        int t  = bid * 256 + tid;            // < 36864
        int u  = t & 3;
        int f  = (t >> 2) & 127;
        int cq = (t >> 9) & 3;
        int gk = t >> 11;                    // ki*2 + g
        int g  = gk & 1;
        int ki = gk >> 1;
        int c  = cq * 16 + g * 8 + u * 2;
        int wlo = (int)kern[(ki * 64 + c    ) * 128 + f];   // src [ki][c][f]
        int whi = (int)kern[(ki * 64 + c + 1) * 128 + f];
        ws[t] = (uint32_t)(uint16_t)(int16_t)wlo |
                ((uint32_t)(uint16_t)(int16_t)whi << 16);
    } else {
        int t = (bid - 144) * 256 + tid;     // < 147968
        if (t >= NXPK) return;
        int c2    = t & 31;
        int rest  = t >> 5;                  // b*34*34 + hp*34 + wp
        int wp    = rest % 34;
        int rest2 = rest / 34;
        int hp    = rest2 % 34;
        int b     = rest2 / 34;
        int v = 0;
        if (hp >= 1 && hp <= 32 && wp >= 1 && wp <= 32) {
            const float* p = &input[(((b * 32) + hp - 1) * 32 + (wp - 1)) * 64 + c2 * 2];
            v = (int)p[0] | ((int)p[1] << 16);
        }
        ws[XOFF + t] = (uint32_t)v;
    }
}

// 512 blocks x 512 threads. Block = (b, h, wtile): 8 output cols x 128 f.
// Thread (cq = tid>>7, f = tid&127): 16-channel x 9-position weight slice in
// 18 int4 VGPRs (loaded once, coalesced); 8 pixel partial sums; LDS reduce.
__global__ __launch_bounds__(512, 4) void conv_main(const uint32_t* __restrict__ ws,
                                                    const float* __restrict__ bias,
                                                    float* __restrict__ out) {
    const uint32_t* xpk = ws + XOFF;

    int bid = blockIdx.x;
    int wt  = bid & 3;
    int h   = (bid >> 2) & 31;
    int b   = bid >> 7;
    int tid = threadIdx.x;
    int f   = tid & 127;
    int cq  = tid >> 7;          // wave-uniform
    int w0  = wt * 8;

    __shared__ uint32_t xl[3 * 10 * 32];   // [row][col 0..9][c2]  3.75 KB
    __shared__ int prt[4 * 8 * 128];       // partial [cq][px][f]  16 KB

    // stage x-patch: 960 dwords (pre-padded global -> no bounds checks)
    for (int k = tid; k < 960; k += 512) {
        int c2  = k & 31;
        int rc  = k >> 5;
        int col = rc % 10;
        int r   = rc / 10;
        xl[k] = xpk[((b * 34 + h + r) * 34 + (w0 + col)) * 32 + c2];
    }

    // weight slice -> 72 VGPRs, one coalesced pass (1 KB/wave/instr)
    int4 wv[18];
    const int4* wp = (const int4*)ws;
    #pragma unroll
    for (int i = 0; i < 18; ++i) wv[i] = wp[i * 512 + tid];

    __syncthreads();

    s16x2 acc[8] = {};

    #pragma unroll
    for (int ki = 0; ki < 9; ++ki) {
        const int row = ki / 3, jj = ki % 3;
        #pragma unroll
        for (int g = 0; g < 2; ++g) {
            const int4 w4 = wv[ki * 2 + g];
            const uint32_t* xrow = xl + (row * 10 + jj) * 32 + cq * 8 + g * 4;
            #pragma unroll
            for (int pb = 0; pb < 2; ++pb) {   // pixel batches of 4 (VGPR cap)
                int4 xv0 = *(const int4*)(xrow + (pb * 4 + 0) * 32);  // bcast b128
                int4 xv1 = *(const int4*)(xrow + (pb * 4 + 1) * 32);
                int4 xv2 = *(const int4*)(xrow + (pb * 4 + 2) * 32);
                int4 xv3 = *(const int4*)(xrow + (pb * 4 + 3) * 32);
                #pragma unroll
                for (int u = 0; u < 4; ++u) {
                    s16x2 w2 = __builtin_bit_cast(s16x2, (&w4.x)[u]);
                    s16x2 A  = (w2 >> 15) & (short)15;   // 15 where w<0
                    acc[pb*4+0] += (__builtin_bit_cast(s16x2, (&xv0.x)[u]) * w2 + A) >> 4;
                    acc[pb*4+1] += (__builtin_bit_cast(s16x2, (&xv1.x)[u]) * w2 + A) >> 4;
                    acc[pb*4+2] += (__builtin_bit_cast(s16x2, (&xv2.x)[u]) * w2 + A) >> 4;
                    acc[pb*4+3] += (__builtin_bit_cast(s16x2, (&xv3.x)[u]) * w2 + A) >> 4;
                }
            }
        }
    }

    // per-thread horizontal add (2 channel halves), stash partial
    #pragma unroll
    for (int px = 0; px < 8; ++px) {
        int a = __builtin_bit_cast(int, acc[px]);
        prt[(cq * 8 + px) * 128 + f] = (int)(short)(a & 0xffff) + (a >> 16);
    }
    __syncthreads();

    // reduce 4 c-quarters, bias, relu, store: 1024 outputs / 512 threads
    for (int k = tid; k < 1024; k += 512) {
        int ff = k & 127;
        int px = k >> 7;
        int v = prt[px * 128 + ff] + prt[(8 + px) * 128 + ff] +
                prt[(16 + px) * 128 + ff] + prt[(24 + px) * 128 + ff] +
                (int)bias[ff];
        out[((b * 32 + h) * 32 + w0 + px) * 128 + ff] = (float)(v < 0 ? 0 : v);
    }
}

extern "C" void kernel_launch(void* const* d_in, const int* in_sizes, int n_in,
                              void* d_out, int out_size, void* d_ws, size_t ws_size,
                              hipStream_t stream) {
    const float* input  = (const float*)d_in[0];   // [4,32,32,64]
    const float* kernel = (const float*)d_in[1];   // [3,3,64,128]
    const float* bias   = (const float*)d_in[2];   // [128]
    // d_in[3] = bits (==4, baked into the closed form)

    uint32_t* ws = (uint32_t*)d_ws;                // 36864 + 147968 dwords used

    prep_all<<<144 + 579, 256, 0, stream>>>(kernel, input, ws);
    conv_main<<<512, 512, 0, stream>>>(ws, bias, (float*)d_out);
}

// Round 5
// 78.146 us; speedup vs baseline: 1.0425x; 1.0425x over previous
//
#include <hip/hip_runtime.h>
#include <stdint.h>

// Bit-serial conv2d closed form: term = sign(w) * ((x * |w|) >> 4)
//                                     = (x * w + A) >> 4   [arith shift]
// where A = (w<0) ? 15 : 0.  x in [0,15], w in [-8,7].
// out = relu(bias + sum_{3x3,c} term).  B=4 H=32 W=32 C=64 F=128.
// Exact in i16 (per-thread |acc| <= 7*144 = 1008).

typedef short s16x2 __attribute__((ext_vector_type(2)));

#define NWPK 36864            // 9*2*512*4 packed weight dwords (2 i16 each)
#define XOFF 36864            // dword offset of padded x in ws
#define NXPK 147968           // 4*34*34*32 padded input dwords (2 i16 each)

// blocks [0,144): weight pack (VGPR-slice layout); [144,723): pad+pack x.
// Weight dword index: ((ki*2+g)*512 + cq*128 + f)*4 + u
//   holds channels c = cq*16 + g*8 + u*2 and c+1 for filter f, position ki.
// -> consumer thread tid=cq*128+f loads int4 at dword 4*((ki*2+g)*512 + tid).
__global__ __launch_bounds__(256) void prep_all(const float* __restrict__ kern,
                                                const float* __restrict__ input,
                                                uint32_t* __restrict__ ws) {
    int bid = blockIdx.x, tid = threadIdx.x;
    if (bid < 144) {
        int t  = bid * 256 + tid;            // < 36864
        int u  = t & 3;
        int f  = (t >> 2) & 127;
        int cq = (t >> 9) & 3;
        int gk = t >> 11;                    // ki*2 + g
        int g  = gk & 1;
        int ki = gk >> 1;
        int c  = cq * 16 + g * 8 + u * 2;
        int wlo = (int)kern[(ki * 64 + c    ) * 128 + f];   // src [ki][c][f]
        int whi = (int)kern[(ki * 64 + c + 1) * 128 + f];
        ws[t] = (uint32_t)(uint16_t)(int16_t)wlo |
                ((uint32_t)(uint16_t)(int16_t)whi << 16);
    } else {
        int t = (bid - 144) * 256 + tid;     // < 147968
        if (t >= NXPK) return;
        int c2    = t & 31;
        int rest  = t >> 5;                  // b*34*34 + hp*34 + wp
        int wp    = rest % 34;
        int rest2 = rest / 34;
        int hp    = rest2 % 34;
        int b     = rest2 / 34;
        int v = 0;
        if (hp >= 1 && hp <= 32 && wp >= 1 && wp <= 32) {
            const float* p = &input[(((b * 32) + hp - 1) * 32 + (wp - 1)) * 64 + c2 * 2];
            v = (int)p[0] | ((int)p[1] << 16);
        }
        ws[XOFF + t] = (uint32_t)v;
    }
}

// 1024 blocks x 512 threads. Block = (b, h, wq): 4 output cols x 128 f.
// Thread (cq = tid>>7, f = tid&127): 16-ch x 9-pos weight slice in 18 int4
// VGPRs (72 regs, loaded once, coalesced); 4 pixel partials; LDS reduce.
// Live set ~100 VGPR < 128 cap (launch_bounds(512,4)) -> no spill headroom
// issue, ~2 x-batches schedulable in flight.
__global__ __launch_bounds__(512, 4) void conv_main(const uint32_t* __restrict__ ws,
                                                    const float* __restrict__ bias,
                                                    float* __restrict__ out) {
    const uint32_t* xpk = ws + XOFF;

    int bid = blockIdx.x;
    int wq  = bid & 7;
    int h   = (bid >> 3) & 31;
    int b   = bid >> 8;
    int tid = threadIdx.x;
    int f   = tid & 127;
    int cq  = tid >> 7;          // wave-uniform
    int w0  = wq * 4;

    __shared__ uint32_t xl[3 * 6 * 32];    // [row][col 0..5][c2]   2.25 KB
    __shared__ int prt[4 * 4 * 128];       // partial [cq][px][f]   8 KB

    // stage x-patch: 576 dwords (pre-padded global -> no bounds checks)
    if (tid < 576) {
        int c2  = tid & 31;
        int rc  = tid >> 5;
        int col = rc % 6;
        int r   = rc / 6;
        xl[tid] = xpk[((b * 34 + h + r) * 34 + (w0 + col)) * 32 + c2];
    } else {
        int k   = tid - 512;     // 64 remaining dwords: k in [0,64) handled above
    }
    if (tid < 64) {              // dwords 512..575
        int k   = tid + 512;
        int c2  = k & 31;
        int rc  = k >> 5;
        int col = rc % 6;
        int r   = rc / 6;
        xl[k] = xpk[((b * 34 + h + r) * 34 + (w0 + col)) * 32 + c2];
    }

    // weight slice -> 72 VGPRs, one coalesced pass (1 KB/wave/instr, L2-hot)
    int4 wv[18];
    const int4* wp = (const int4*)ws;
    #pragma unroll
    for (int i = 0; i < 18; ++i) wv[i] = wp[i * 512 + tid];

    __syncthreads();

    s16x2 acc0 = {0,0}, acc1 = {0,0}, acc2 = {0,0}, acc3 = {0,0};

    #pragma unroll
    for (int ki = 0; ki < 9; ++ki) {
        const int row = ki / 3, jj = ki % 3;
        #pragma unroll
        for (int g = 0; g < 2; ++g) {
            const int4 w4 = wv[ki * 2 + g];
            const uint32_t* xrow = xl + (row * 6 + jj) * 32 + cq * 8 + g * 4;
            int4 xv0 = *(const int4*)(xrow);        // px 0, ds_read_b128 bcast
            int4 xv1 = *(const int4*)(xrow + 32);   // px 1
            int4 xv2 = *(const int4*)(xrow + 64);   // px 2
            int4 xv3 = *(const int4*)(xrow + 96);   // px 3
            #pragma unroll
            for (int u = 0; u < 4; ++u) {
                s16x2 w2 = __builtin_bit_cast(s16x2, (&w4.x)[u]);
                s16x2 A  = (w2 >> 15) & (short)15;   // 15 where w<0
                acc0 += (__builtin_bit_cast(s16x2, (&xv0.x)[u]) * w2 + A) >> 4;
                acc1 += (__builtin_bit_cast(s16x2, (&xv1.x)[u]) * w2 + A) >> 4;
                acc2 += (__builtin_bit_cast(s16x2, (&xv2.x)[u]) * w2 + A) >> 4;
                acc3 += (__builtin_bit_cast(s16x2, (&xv3.x)[u]) * w2 + A) >> 4;
            }
        }
    }

    // per-thread horizontal add (2 channel halves), stash partial
    int a;
    a = __builtin_bit_cast(int, acc0); prt[(cq * 4 + 0) * 128 + f] = (int)(short)(a & 0xffff) + (a >> 16);
    a = __builtin_bit_cast(int, acc1); prt[(cq * 4 + 1) * 128 + f] = (int)(short)(a & 0xffff) + (a >> 16);
    a = __builtin_bit_cast(int, acc2); prt[(cq * 4 + 2) * 128 + f] = (int)(short)(a & 0xffff) + (a >> 16);
    a = __builtin_bit_cast(int, acc3); prt[(cq * 4 + 3) * 128 + f] = (int)(short)(a & 0xffff) + (a >> 16);
    __syncthreads();

    // reduce 4 c-quarters, bias, relu, store: 512 outputs / 512 threads
    {
        int ff = tid & 127;
        int px = tid >> 7;
        int v = prt[(0 * 4 + px) * 128 + ff] + prt[(1 * 4 + px) * 128 + ff] +
                prt[(2 * 4 + px) * 128 + ff] + prt[(3 * 4 + px) * 128 + ff] +
                (int)bias[ff];
        out[((b * 32 + h) * 32 + w0 + px) * 128 + ff] = (float)(v < 0 ? 0 : v);
    }
}

extern "C" void kernel_launch(void* const* d_in, const int* in_sizes, int n_in,
                              void* d_out, int out_size, void* d_ws, size_t ws_size,
                              hipStream_t stream) {
    const float* input  = (const float*)d_in[0];   // [4,32,32,64]
    const float* kernel = (const float*)d_in[1];   // [3,3,64,128]
    const float* bias   = (const float*)d_in[2];   // [128]
    // d_in[3] = bits (==4, baked into the closed form)

    uint32_t* ws = (uint32_t*)d_ws;                // 36864 + 147968 dwords used

    prep_all<<<144 + 579, 256, 0, stream>>>(kernel, input, ws);
    conv_main<<<1024, 512, 0, stream>>>(ws, bias, (float*)d_out);
}